// Round 9
// baseline (86.214 us; speedup 1.0000x reference)
//
#include <hip/hip_runtime.h>
#include <hip/hip_bf16.h>

typedef float f32x4 __attribute__((ext_vector_type(4)));
typedef float f32x2 __attribute__((ext_vector_type(2)));
typedef int   i32x8 __attribute__((ext_vector_type(8)));

#define DDIM 128
#define TM 128          // rows of X per block
#define JCOLS 512       // cols of Y per block
#define NBLK 1024       // (8192/TM)*(8192/JCOLS)
#define MARGIN_F 0.2f

// ============================ fast path (MX-fp8, K=128) ============================
// prep: quantize 2*x and y to fp8 e4m3 in mfma_scale_16x16x128 operand order.
// Fragment f covers 16 rows; lane l = q*16 + (row&15) holds k = 32q..32q+31 (32 B).
// dst = f*2048 + l*32 + (k - 32q).  Same transform for x and y, so any internal
// k-permutation of the instruction cancels in the dot product (unit scales).
// Also yy[i]=||y_i||^2, crow[i]=yy_i-2*x_i.y_i+margin (fp32), counter=0.
__global__ __launch_bounds__(256)
void prep_v9_kernel(const float* __restrict__ x, const float* __restrict__ y,
                    char* __restrict__ xq, char* __restrict__ yq,
                    float* __restrict__ yy, float* __restrict__ crow,
                    unsigned int* __restrict__ counter)
{
    const int t   = threadIdx.x;
    const int row = blockIdx.x * 16 + (t >> 4);
    const int c   = t & 15;                       // 8-elem k-chunk (k = c*8..c*8+7)
    const float* xr = x + (size_t)row * DDIM + c * 8;
    const float* yr = y + (size_t)row * DDIM + c * 8;
    const float4 xa = *(const float4*)xr;
    const float4 xc = *(const float4*)(xr + 4);
    const float4 ya = *(const float4*)yr;
    const float4 yc = *(const float4*)(yr + 4);

    int x01 = __builtin_amdgcn_cvt_pk_fp8_f32(2.0f*xa.x, 2.0f*xa.y, 0, false);
    int x23 = __builtin_amdgcn_cvt_pk_fp8_f32(2.0f*xa.z, 2.0f*xa.w, 0, false);
    int x45 = __builtin_amdgcn_cvt_pk_fp8_f32(2.0f*xc.x, 2.0f*xc.y, 0, false);
    int x67 = __builtin_amdgcn_cvt_pk_fp8_f32(2.0f*xc.z, 2.0f*xc.w, 0, false);
    int y01 = __builtin_amdgcn_cvt_pk_fp8_f32(ya.x, ya.y, 0, false);
    int y23 = __builtin_amdgcn_cvt_pk_fp8_f32(ya.z, ya.w, 0, false);
    int y45 = __builtin_amdgcn_cvt_pk_fp8_f32(yc.x, yc.y, 0, false);
    int y67 = __builtin_amdgcn_cvt_pk_fp8_f32(yc.z, yc.w, 0, false);
    int2 xp, yp;
    xp.x = (x01 & 0xffff) | (x23 << 16);  xp.y = (x45 & 0xffff) | (x67 << 16);
    yp.x = (y01 & 0xffff) | (y23 << 16);  yp.y = (y45 & 0xffff) | (y67 << 16);

    // lane = (c>>2)*16 + (row&15); within-lane byte = (c&3)*8
    const size_t base = (size_t)(row >> 4) * 2048
                      + (size_t)((c >> 2) * 16 + (row & 15)) * 32 + (size_t)(c & 3) * 8;
    *(int2*)(xq + base) = xp;
    *(int2*)(yq + base) = yp;

    float sy  = ya.x*ya.x + ya.y*ya.y + ya.z*ya.z + ya.w*ya.w
              + yc.x*yc.x + yc.y*yc.y + yc.z*yc.z + yc.w*yc.w;
    float sxy = xa.x*ya.x + xa.y*ya.y + xa.z*ya.z + xa.w*ya.w
              + xc.x*yc.x + xc.y*yc.y + xc.z*yc.z + xc.w*yc.w;
    #pragma unroll
    for (int o = 8; o; o >>= 1) {
        sy  += __shfl_xor(sy,  o);
        sxy += __shfl_xor(sxy, o);
    }
    if (c == 0) {
        yy[row]   = sy;
        crow[row] = sy - 2.0f * sxy + MARGIN_F;
    }
    if (t == 0 && blockIdx.x == 0) *counter = 0u;   // ws is re-poisoned each launch
}

// fused MX-fp8 K=128 GEMM + epilogue + last-block final reduction.
// v7 mapping (proven fastest): 2x2 waves, 64 rows x 256 cols each, 4 blocks/CU,
// 1024 blocks = exactly one resident generation. No LDS/barriers/branches in loop.
__global__ __launch_bounds__(256, 4)
void triplet_v9_kernel(const char* __restrict__ xq, const char* __restrict__ yq,
                       const float* __restrict__ yy, const float* __restrict__ crow,
                       float* __restrict__ partials, unsigned int* __restrict__ counter,
                       float* __restrict__ out, float inv_n2, float diag_corr)
{
    __shared__ float wsum[4];
    __shared__ int   last_flag;
    const int t    = threadIdx.x;
    const int w    = t >> 6;
    const int lane = t & 63;
    const int l4   = lane >> 4;
    const int l15  = lane & 15;
    const int wm   = w >> 1;            // 2x2 waves: 64 rows x 256 cols each
    const int wn   = w & 1;
    const int jg     = blockIdx.x;      // 0..15  (512-col group)
    const int istrip = blockIdx.y;      // 0..63  (128-row strip)

    // ---- hoist A fragments: 8 coalesced 16B loads -> 32 VGPRs ----
    i32x8 af[4];                        // [mi]
    {
        const char* ap = xq + (size_t)(istrip * 8 + wm * 4) * 2048 + (size_t)lane * 32;
        #pragma unroll
        for (int mi = 0; mi < 4; ++mi) {
            const int4 p0 = *(const int4*)(ap + mi * 2048);
            const int4 p1 = *(const int4*)(ap + mi * 2048 + 16);
            af[mi] = (i32x8){p0.x, p0.y, p0.z, p0.w, p1.x, p1.y, p1.z, p1.w};
        }
    }
    const int rlo = istrip * TM + wm * 64;
    f32x2 ctv[8];                       // crow for rows (mi, 2rp..2rp+1)
    #pragma unroll
    for (int mi = 0; mi < 4; ++mi) {
        const float4 c4 = *(const float4*)&crow[rlo + mi * 16 + l4 * 4];
        ctv[mi*2+0] = (f32x2){c4.x, c4.y};
        ctv[mi*2+1] = (f32x2){c4.z, c4.w};
    }
    // ---- preload yy for this wave's 16 column fragments ----
    const int cb0 = jg * 32 + wn * 16;
    float yyv[16];
    #pragma unroll
    for (int s = 0; s < 16; ++s)
        yyv[s] = yy[(cb0 + s) * 16 + l15];

    f32x2 lsum2[2] = {(f32x2){0.f,0.f}, (f32x2){0.f,0.f}};

    #pragma unroll
    for (int s = 0; s < 16; ++s) {
        const char* bp = yq + (size_t)(cb0 + s) * 2048 + (size_t)lane * 32;
        const int4 q0 = *(const int4*)(bp);
        const int4 q1 = *(const int4*)(bp + 16);
        const i32x8 bfv = (i32x8){q0.x, q0.y, q0.z, q0.w, q1.x, q1.y, q1.z, q1.w};

        f32x4 acc[4] = {};
        #pragma unroll
        for (int mi = 0; mi < 4; ++mi)
            acc[mi] = __builtin_amdgcn_mfma_scale_f32_16x16x128_f8f6f4(
                af[mi], bfv, acc[mi], 0, 0,      // fmt A = fp8, fmt B = fp8
                0, 127, 0, 127);                 // unit scales (E8M0 = 127)

        // epilogue: relu(2S + crow_row - yy_col), packed f32 pairs, branch-free
        const f32x2 yy2 = (f32x2){yyv[s], yyv[s]};
        #pragma unroll
        for (int mi = 0; mi < 4; ++mi) {
            #pragma unroll
            for (int rp = 0; rp < 2; ++rp) {
                f32x2 a = (f32x2){acc[mi][2*rp], acc[mi][2*rp+1]};
                a = a + (ctv[mi*2+rp] - yy2);
                lsum2[rp] += __builtin_elementwise_max(a, (f32x2){0.f, 0.f});
            }
        }
    }

    float ls = (lsum2[0][0] + lsum2[0][1]) + (lsum2[1][0] + lsum2[1][1]);
    #pragma unroll
    for (int off = 32; off; off >>= 1) ls += __shfl_xor(ls, off);
    if (lane == 0) wsum[w] = ls;
    __syncthreads();
    if (t == 0) {
        partials[blockIdx.y * gridDim.x + blockIdx.x] =
            (wsum[0] + wsum[1]) + (wsum[2] + wsum[3]);
        __threadfence();                              // publish partial device-wide
        const unsigned int old = atomicAdd(counter, 1u);
        last_flag = (old == NBLK - 1u) ? 1 : 0;
    }
    __syncthreads();
    if (last_flag) {                                  // last block: final reduction
        __threadfence();                              // acquire all partials
        float s = partials[t] + partials[t + 256] + partials[t + 512] + partials[t + 768];
        #pragma unroll
        for (int off = 32; off; off >>= 1) s += __shfl_xor(s, off);
        if (lane == 0) wsum[w] = s;
        __syncthreads();
        if (t == 0)
            out[0] = ((wsum[0] + wsum[1]) + (wsum[2] + wsum[3])) * inv_n2 + diag_corr;
    }
}

// ====================== fallback path (round-1, fp32 staging) ======================

#define TILE 128
#define LDSK 136
typedef __bf16 bf16x8 __attribute__((ext_vector_type(8)));

__global__ __launch_bounds__(256)
void prep_f32_kernel(const float* __restrict__ x, const float* __restrict__ y,
                     float* __restrict__ yy, float* __restrict__ crow,
                     float* __restrict__ out)
{
    const int t    = threadIdx.x;
    const int lane = t & 63;
    const int row  = blockIdx.x * 4 + (t >> 6);
    const float2 xv = ((const float2*)(x + (size_t)row * DDIM))[lane];
    const float2 yv = ((const float2*)(y + (size_t)row * DDIM))[lane];
    float sy  = yv.x * yv.x + yv.y * yv.y;
    float sxy = xv.x * yv.x + xv.y * yv.y;
    #pragma unroll
    for (int off = 32; off; off >>= 1) {
        sy  += __shfl_xor(sy,  off);
        sxy += __shfl_xor(sxy, off);
    }
    if (lane == 0) { yy[row] = sy; crow[row] = sy - 2.0f * sxy; }
    if (t == 0 && blockIdx.x == 0) out[0] = 0.0f;
}

__global__ __launch_bounds__(256)
void triplet_f32_kernel(const float* __restrict__ x, const float* __restrict__ y,
                        const float* __restrict__ yy, const float* __restrict__ crow,
                        float* __restrict__ out, float inv_n2)
{
    __shared__ __bf16 As[TILE][LDSK];
    __shared__ __bf16 Bs[TILE][LDSK];
    __shared__ float ctile[TILE];
    __shared__ float yytile[TILE];
    __shared__ float wsum[4];

    const int t  = threadIdx.x;
    const int bi = blockIdx.y;
    const int bj = blockIdx.x;
    {
        const int rr = t >> 4;
        const int cc = (t & 15) * 8;
        const float* xp = x + (size_t)bi * TILE * DDIM;
        const float* yp = y + (size_t)bj * TILE * DDIM;
        #pragma unroll
        for (int it = 0; it < 8; ++it) {
            const int r = it * 16 + rr;
            const float4 a0 = *(const float4*)(xp + (size_t)r * DDIM + cc);
            const float4 a1 = *(const float4*)(xp + (size_t)r * DDIM + cc + 4);
            bf16x8 av;
            av[0] = (__bf16)a0.x; av[1] = (__bf16)a0.y; av[2] = (__bf16)a0.z; av[3] = (__bf16)a0.w;
            av[4] = (__bf16)a1.x; av[5] = (__bf16)a1.y; av[6] = (__bf16)a1.z; av[7] = (__bf16)a1.w;
            *(bf16x8*)&As[r][cc] = av;
            const float4 b0 = *(const float4*)(yp + (size_t)r * DDIM + cc);
            const float4 b1 = *(const float4*)(yp + (size_t)r * DDIM + cc + 4);
            bf16x8 bv;
            bv[0] = (__bf16)b0.x; bv[1] = (__bf16)b0.y; bv[2] = (__bf16)b0.z; bv[3] = (__bf16)b0.w;
            bv[4] = (__bf16)b1.x; bv[5] = (__bf16)b1.y; bv[6] = (__bf16)b1.z; bv[7] = (__bf16)b1.w;
            *(bf16x8*)&Bs[r][cc] = bv;
        }
        if (t < TILE) ctile[t]         = crow[bi * TILE + t];
        else          yytile[t - TILE] = yy[bj * TILE + (t - TILE)];
    }
    __syncthreads();

    const int wave = t >> 6;
    const int lane = t & 63;
    const int wm   = wave >> 1;
    const int wn   = wave & 1;
    const int l4   = lane >> 4;
    const int l15  = lane & 15;

    f32x4 acc[4][4] = {};
    #pragma unroll
    for (int kk = 0; kk < 4; ++kk) {
        const int kb = kk * 32 + l4 * 8;
        bf16x8 af[4], bfv[4];
        #pragma unroll
        for (int mi = 0; mi < 4; ++mi) af[mi] = *(const bf16x8*)&As[wm * 64 + mi * 16 + l15][kb];
        #pragma unroll
        for (int ni = 0; ni < 4; ++ni) bfv[ni] = *(const bf16x8*)&Bs[wn * 64 + ni * 16 + l15][kb];
        #pragma unroll
        for (int mi = 0; mi < 4; ++mi)
            #pragma unroll
            for (int ni = 0; ni < 4; ++ni)
                acc[mi][ni] = __builtin_amdgcn_mfma_f32_16x16x32_bf16(af[mi], bfv[ni], acc[mi][ni], 0, 0, 0);
    }

    float lsum = 0.0f;
    #pragma unroll
    for (int ni = 0; ni < 4; ++ni) {
        const int ct    = wn * 64 + ni * 16 + l15;
        const float yyv = yytile[ct];
        const int gj    = bj * TILE + ct;
        #pragma unroll
        for (int mi = 0; mi < 4; ++mi)
            #pragma unroll
            for (int r = 0; r < 4; ++r) {
                const int rt = wm * 64 + mi * 16 + l4 * 4 + r;
                float v = fmaxf(2.0f * acc[mi][ni][r] + ctile[rt] - yyv + MARGIN_F, 0.0f);
                if (bi * TILE + rt == gj) v = 0.0f;
                lsum += v;
            }
    }
    #pragma unroll
    for (int off = 32; off; off >>= 1) lsum += __shfl_xor(lsum, off);
    if (lane == 0) wsum[wave] = lsum;
    __syncthreads();
    if (t == 0) atomicAdd(out, (wsum[0] + wsum[1] + wsum[2] + wsum[3]) * inv_n2);
}

// ================================ launch ================================

extern "C" void kernel_launch(void* const* d_in, const int* in_sizes, int n_in,
                              void* d_out, int out_size, void* d_ws, size_t ws_size,
                              hipStream_t stream)
{
    const float* x = (const float*)d_in[0];
    const float* y = (const float*)d_in[1];
    float* out = (float*)d_out;
    const int N = in_sizes[0] / DDIM;          // 8192
    const float inv_n2 = 1.0f / ((float)N * (float)N);

    const size_t q_bytes = (size_t)N * DDIM;   // 1 MB each (fp8)
    const size_t need = 2 * q_bytes + 2 * (size_t)N * sizeof(float)
                      + (NBLK + 1) * sizeof(float);

    if (ws_size >= need && N == 8192) {
        char*  xq  = (char*)d_ws;
        char*  yq  = xq + q_bytes;
        float* yy  = (float*)(yq + q_bytes);
        float* crw = yy + N;
        float* par = crw + N;                  // NBLK partials
        unsigned int* cnt = (unsigned int*)(par + NBLK);
        const float diag_corr = -MARGIN_F / (float)N;  // remove the N diagonal margin terms
        prep_v9_kernel<<<dim3(N / 16), dim3(256), 0, stream>>>(x, y, xq, yq, yy, crw, cnt);
        triplet_v9_kernel<<<dim3(N / JCOLS, N / TM), dim3(256), 0, stream>>>(
            xq, yq, yy, crw, par, cnt, out, inv_n2, diag_corr);
    } else {
        float* yy  = (float*)d_ws;
        float* crw = yy + N;
        prep_f32_kernel<<<dim3(N / 4), dim3(256), 0, stream>>>(x, y, yy, crw, out);
        triplet_f32_kernel<<<dim3(N / TILE, N / TILE), dim3(256), 0, stream>>>(
            x, y, yy, crw, out, inv_n2);
    }
}

// Round 10
// 71.254 us; speedup vs baseline: 1.2100x; 1.2100x over previous
//
#include <hip/hip_runtime.h>
#include <hip/hip_bf16.h>

typedef float f32x4 __attribute__((ext_vector_type(4)));
typedef float f32x2 __attribute__((ext_vector_type(2)));
typedef int   i32x8 __attribute__((ext_vector_type(8)));

#define DDIM 128
#define TM 128          // rows of X per block
#define JCOLS 512       // cols of Y per block
#define MARGIN_F 0.2f

// ============================ fast path (MX-fp8, K=128) ============================
// prep: quantize 2*x and y to fp8 e4m3 in mfma_scale_16x16x128 operand order.
// Fragment f covers 16 rows; lane l = q*16 + (row&15) holds k = 32q..32q+31 (32 B).
// dst = f*2048 + l*32 + (k - 32q).  Same transform for x and y, so any internal
// k-permutation of the instruction cancels in the dot product (unit scales).
// Also yy[i]=||y_i||^2, crow[i]=yy_i-2*x_i.y_i+margin (fp32, exact inputs).
__global__ __launch_bounds__(256)
void prep_v7_kernel(const float* __restrict__ x, const float* __restrict__ y,
                    char* __restrict__ xq, char* __restrict__ yq,
                    float* __restrict__ yy, float* __restrict__ crow)
{
    const int t   = threadIdx.x;
    const int row = blockIdx.x * 16 + (t >> 4);
    const int c   = t & 15;                       // 8-elem k-chunk (k = c*8..c*8+7)
    const float* xr = x + (size_t)row * DDIM + c * 8;
    const float* yr = y + (size_t)row * DDIM + c * 8;
    const float4 xa = *(const float4*)xr;
    const float4 xc = *(const float4*)(xr + 4);
    const float4 ya = *(const float4*)yr;
    const float4 yc = *(const float4*)(yr + 4);

    int x01 = __builtin_amdgcn_cvt_pk_fp8_f32(2.0f*xa.x, 2.0f*xa.y, 0, false);
    int x23 = __builtin_amdgcn_cvt_pk_fp8_f32(2.0f*xa.z, 2.0f*xa.w, 0, false);
    int x45 = __builtin_amdgcn_cvt_pk_fp8_f32(2.0f*xc.x, 2.0f*xc.y, 0, false);
    int x67 = __builtin_amdgcn_cvt_pk_fp8_f32(2.0f*xc.z, 2.0f*xc.w, 0, false);
    int y01 = __builtin_amdgcn_cvt_pk_fp8_f32(ya.x, ya.y, 0, false);
    int y23 = __builtin_amdgcn_cvt_pk_fp8_f32(ya.z, ya.w, 0, false);
    int y45 = __builtin_amdgcn_cvt_pk_fp8_f32(yc.x, yc.y, 0, false);
    int y67 = __builtin_amdgcn_cvt_pk_fp8_f32(yc.z, yc.w, 0, false);
    int2 xp, yp;
    xp.x = (x01 & 0xffff) | (x23 << 16);  xp.y = (x45 & 0xffff) | (x67 << 16);
    yp.x = (y01 & 0xffff) | (y23 << 16);  yp.y = (y45 & 0xffff) | (y67 << 16);

    // lane = (c>>2)*16 + (row&15); within-lane byte = (c&3)*8
    const size_t base = (size_t)(row >> 4) * 2048
                      + (size_t)((c >> 2) * 16 + (row & 15)) * 32 + (size_t)(c & 3) * 8;
    *(int2*)(xq + base) = xp;
    *(int2*)(yq + base) = yp;

    float sy  = ya.x*ya.x + ya.y*ya.y + ya.z*ya.z + ya.w*ya.w
              + yc.x*yc.x + yc.y*yc.y + yc.z*yc.z + yc.w*yc.w;
    float sxy = xa.x*ya.x + xa.y*ya.y + xa.z*ya.z + xa.w*ya.w
              + xc.x*yc.x + xc.y*yc.y + xc.z*yc.z + xc.w*yc.w;
    #pragma unroll
    for (int o = 8; o; o >>= 1) {
        sy  += __shfl_xor(sy,  o);
        sxy += __shfl_xor(sxy, o);
    }
    if (c == 0) {
        yy[row]   = sy;
        crow[row] = sy - 2.0f * sxy + MARGIN_F;
    }
}

// fused MX-fp8 K=128 GEMM + epilogue; per-block partial -> partials[] (no atomics).
// No LDS / no barriers / no branches in the hot loop; 4 blocks/CU, one generation.
__global__ __launch_bounds__(256, 4)
void triplet_v7_kernel(const char* __restrict__ xq, const char* __restrict__ yq,
                       const float* __restrict__ yy, const float* __restrict__ crow,
                       float* __restrict__ partials)
{
    __shared__ float wsum[4];
    const int t    = threadIdx.x;
    const int w    = t >> 6;
    const int lane = t & 63;
    const int l4   = lane >> 4;
    const int l15  = lane & 15;
    const int wm   = w >> 1;            // 2x2 waves: 64 rows x 256 cols each
    const int wn   = w & 1;
    const int jg     = blockIdx.x;      // 0..15  (512-col group)
    const int istrip = blockIdx.y;      // 0..63  (128-row strip)

    // ---- hoist A fragments: 8 coalesced 16B loads -> 32 VGPRs ----
    i32x8 af[4];                        // [mi]
    {
        const char* ap = xq + (size_t)(istrip * 8 + wm * 4) * 2048 + (size_t)lane * 32;
        #pragma unroll
        for (int mi = 0; mi < 4; ++mi) {
            const int4 p0 = *(const int4*)(ap + mi * 2048);
            const int4 p1 = *(const int4*)(ap + mi * 2048 + 16);
            af[mi] = (i32x8){p0.x, p0.y, p0.z, p0.w, p1.x, p1.y, p1.z, p1.w};
        }
    }
    const int rlo = istrip * TM + wm * 64;
    f32x2 ctv[8];                       // crow for rows (mi, 2rp..2rp+1)
    #pragma unroll
    for (int mi = 0; mi < 4; ++mi) {
        const float4 c4 = *(const float4*)&crow[rlo + mi * 16 + l4 * 4];
        ctv[mi*2+0] = (f32x2){c4.x, c4.y};
        ctv[mi*2+1] = (f32x2){c4.z, c4.w};
    }
    // ---- preload yy for this wave's 16 column fragments ----
    const int cb0 = jg * 32 + wn * 16;
    float yyv[16];
    #pragma unroll
    for (int s = 0; s < 16; ++s)
        yyv[s] = yy[(cb0 + s) * 16 + l15];

    f32x2 lsum2[2] = {(f32x2){0.f,0.f}, (f32x2){0.f,0.f}};

    #pragma unroll
    for (int s = 0; s < 16; ++s) {
        const char* bp = yq + (size_t)(cb0 + s) * 2048 + (size_t)lane * 32;
        const int4 q0 = *(const int4*)(bp);
        const int4 q1 = *(const int4*)(bp + 16);
        const i32x8 bfv = (i32x8){q0.x, q0.y, q0.z, q0.w, q1.x, q1.y, q1.z, q1.w};

        f32x4 acc[4] = {};
        #pragma unroll
        for (int mi = 0; mi < 4; ++mi)
            acc[mi] = __builtin_amdgcn_mfma_scale_f32_16x16x128_f8f6f4(
                af[mi], bfv, acc[mi], 0, 0,      // fmt A = fp8, fmt B = fp8
                0, 127, 0, 127);                 // unit scales (E8M0 = 127)

        // epilogue: relu(2S + crow_row - yy_col), packed f32 pairs, branch-free
        const f32x2 yy2 = (f32x2){yyv[s], yyv[s]};
        #pragma unroll
        for (int mi = 0; mi < 4; ++mi) {
            #pragma unroll
            for (int rp = 0; rp < 2; ++rp) {
                f32x2 a = (f32x2){acc[mi][2*rp], acc[mi][2*rp+1]};
                a = a + (ctv[mi*2+rp] - yy2);
                lsum2[rp] += __builtin_elementwise_max(a, (f32x2){0.f, 0.f});
            }
        }
    }

    float ls = (lsum2[0][0] + lsum2[0][1]) + (lsum2[1][0] + lsum2[1][1]);
    #pragma unroll
    for (int off = 32; off; off >>= 1) ls += __shfl_xor(ls, off);
    if (lane == 0) wsum[w] = ls;
    __syncthreads();
    if (t == 0)
        partials[blockIdx.y * gridDim.x + blockIdx.x] =
            (wsum[0] + wsum[1]) + (wsum[2] + wsum[3]);
}

// deterministic final reduction of 1024 partials; folds scale + diagonal correction
__global__ __launch_bounds__(256)
void reduce_v7_kernel(const float* __restrict__ partials, float* __restrict__ out,
                      float inv_n2, float diag_corr)
{
    __shared__ float wsum[4];
    const int t = threadIdx.x;
    float s = partials[t] + partials[t + 256] + partials[t + 512] + partials[t + 768];
    #pragma unroll
    for (int off = 32; off; off >>= 1) s += __shfl_xor(s, off);
    if ((t & 63) == 0) wsum[t >> 6] = s;
    __syncthreads();
    if (t == 0)
        out[0] = ((wsum[0] + wsum[1]) + (wsum[2] + wsum[3])) * inv_n2 + diag_corr;
}

// ====================== fallback path (round-1, fp32 staging) ======================

#define TILE 128
#define LDSK 136
typedef __bf16 bf16x8 __attribute__((ext_vector_type(8)));

__global__ __launch_bounds__(256)
void prep_f32_kernel(const float* __restrict__ x, const float* __restrict__ y,
                     float* __restrict__ yy, float* __restrict__ crow,
                     float* __restrict__ out)
{
    const int t    = threadIdx.x;
    const int lane = t & 63;
    const int row  = blockIdx.x * 4 + (t >> 6);
    const float2 xv = ((const float2*)(x + (size_t)row * DDIM))[lane];
    const float2 yv = ((const float2*)(y + (size_t)row * DDIM))[lane];
    float sy  = yv.x * yv.x + yv.y * yv.y;
    float sxy = xv.x * yv.x + xv.y * yv.y;
    #pragma unroll
    for (int off = 32; off; off >>= 1) {
        sy  += __shfl_xor(sy,  off);
        sxy += __shfl_xor(sxy, off);
    }
    if (lane == 0) { yy[row] = sy; crow[row] = sy - 2.0f * sxy; }
    if (t == 0 && blockIdx.x == 0) out[0] = 0.0f;
}

__global__ __launch_bounds__(256)
void triplet_f32_kernel(const float* __restrict__ x, const float* __restrict__ y,
                        const float* __restrict__ yy, const float* __restrict__ crow,
                        float* __restrict__ out, float inv_n2)
{
    __shared__ __bf16 As[TILE][LDSK];
    __shared__ __bf16 Bs[TILE][LDSK];
    __shared__ float ctile[TILE];
    __shared__ float yytile[TILE];
    __shared__ float wsum[4];

    const int t  = threadIdx.x;
    const int bi = blockIdx.y;
    const int bj = blockIdx.x;
    {
        const int rr = t >> 4;
        const int cc = (t & 15) * 8;
        const float* xp = x + (size_t)bi * TILE * DDIM;
        const float* yp = y + (size_t)bj * TILE * DDIM;
        #pragma unroll
        for (int it = 0; it < 8; ++it) {
            const int r = it * 16 + rr;
            const float4 a0 = *(const float4*)(xp + (size_t)r * DDIM + cc);
            const float4 a1 = *(const float4*)(xp + (size_t)r * DDIM + cc + 4);
            bf16x8 av;
            av[0] = (__bf16)a0.x; av[1] = (__bf16)a0.y; av[2] = (__bf16)a0.z; av[3] = (__bf16)a0.w;
            av[4] = (__bf16)a1.x; av[5] = (__bf16)a1.y; av[6] = (__bf16)a1.z; av[7] = (__bf16)a1.w;
            *(bf16x8*)&As[r][cc] = av;
            const float4 b0 = *(const float4*)(yp + (size_t)r * DDIM + cc);
            const float4 b1 = *(const float4*)(yp + (size_t)r * DDIM + cc + 4);
            bf16x8 bv;
            bv[0] = (__bf16)b0.x; bv[1] = (__bf16)b0.y; bv[2] = (__bf16)b0.z; bv[3] = (__bf16)b0.w;
            bv[4] = (__bf16)b1.x; bv[5] = (__bf16)b1.y; bv[6] = (__bf16)b1.z; bv[7] = (__bf16)b1.w;
            *(bf16x8*)&Bs[r][cc] = bv;
        }
        if (t < TILE) ctile[t]         = crow[bi * TILE + t];
        else          yytile[t - TILE] = yy[bj * TILE + (t - TILE)];
    }
    __syncthreads();

    const int wave = t >> 6;
    const int lane = t & 63;
    const int wm   = wave >> 1;
    const int wn   = wave & 1;
    const int l4   = lane >> 4;
    const int l15  = lane & 15;

    f32x4 acc[4][4] = {};
    #pragma unroll
    for (int kk = 0; kk < 4; ++kk) {
        const int kb = kk * 32 + l4 * 8;
        bf16x8 af[4], bfv[4];
        #pragma unroll
        for (int mi = 0; mi < 4; ++mi) af[mi] = *(const bf16x8*)&As[wm * 64 + mi * 16 + l15][kb];
        #pragma unroll
        for (int ni = 0; ni < 4; ++ni) bfv[ni] = *(const bf16x8*)&Bs[wn * 64 + ni * 16 + l15][kb];
        #pragma unroll
        for (int mi = 0; mi < 4; ++mi)
            #pragma unroll
            for (int ni = 0; ni < 4; ++ni)
                acc[mi][ni] = __builtin_amdgcn_mfma_f32_16x16x32_bf16(af[mi], bfv[ni], acc[mi][ni], 0, 0, 0);
    }

    float lsum = 0.0f;
    #pragma unroll
    for (int ni = 0; ni < 4; ++ni) {
        const int ct    = wn * 64 + ni * 16 + l15;
        const float yyv = yytile[ct];
        const int gj    = bj * TILE + ct;
        #pragma unroll
        for (int mi = 0; mi < 4; ++mi)
            #pragma unroll
            for (int r = 0; r < 4; ++r) {
                const int rt = wm * 64 + mi * 16 + l4 * 4 + r;
                float v = fmaxf(2.0f * acc[mi][ni][r] + ctile[rt] - yyv + MARGIN_F, 0.0f);
                if (bi * TILE + rt == gj) v = 0.0f;
                lsum += v;
            }
    }
    #pragma unroll
    for (int off = 32; off; off >>= 1) lsum += __shfl_xor(lsum, off);
    if (lane == 0) wsum[wave] = lsum;
    __syncthreads();
    if (t == 0) atomicAdd(out, (wsum[0] + wsum[1] + wsum[2] + wsum[3]) * inv_n2);
}

// ================================ launch ================================

extern "C" void kernel_launch(void* const* d_in, const int* in_sizes, int n_in,
                              void* d_out, int out_size, void* d_ws, size_t ws_size,
                              hipStream_t stream)
{
    const float* x = (const float*)d_in[0];
    const float* y = (const float*)d_in[1];
    float* out = (float*)d_out;
    const int N = in_sizes[0] / DDIM;          // 8192
    const float inv_n2 = 1.0f / ((float)N * (float)N);

    const size_t q_bytes = (size_t)N * DDIM;   // 1 MB each (fp8)
    const size_t need = 2 * q_bytes + 2 * (size_t)N * sizeof(float) + 4096 * sizeof(float);

    if (ws_size >= need && (N % JCOLS) == 0) {
        char*  xq  = (char*)d_ws;
        char*  yq  = xq + q_bytes;
        float* yy  = (float*)(yq + q_bytes);
        float* crw = yy + N;
        float* par = crw + N;                  // 1024 partials
        const float diag_corr = -MARGIN_F / (float)N;  // remove the N diagonal margin terms
        prep_v7_kernel<<<dim3(N / 16), dim3(256), 0, stream>>>(x, y, xq, yq, yy, crw);
        triplet_v7_kernel<<<dim3(N / JCOLS, N / TM), dim3(256), 0, stream>>>(
            xq, yq, yy, crw, par);
        reduce_v7_kernel<<<dim3(1), dim3(256), 0, stream>>>(par, out, inv_n2, diag_corr);
    } else {
        float* yy  = (float*)d_ws;
        float* crw = yy + N;
        prep_f32_kernel<<<dim3(N / 4), dim3(256), 0, stream>>>(x, y, yy, crw, out);
        triplet_f32_kernel<<<dim3(N / TILE, N / TILE), dim3(256), 0, stream>>>(
            x, y, yy, crw, out, inv_n2);
    }
}